// Round 16
// baseline (413.673 us; speedup 1.0000x reference)
//
#include <hip/hip_runtime.h>
#include <hip/hip_fp16.h>

// DEQ classifier, dx-packed 16x16x32 MFMA with ROW-REUSE, 512-thread blocks.
// One block per image (1024 x 512 threads, 8 waves; wave owns 4 output rows,
// acc[4], row-reuse over its 8 pixel rows). LDS: one carved buffer:
//   [0,5184)      zxb plane  (36x36 bundles of 8-ch f16, 16 B each)
//   [5184,10368)  hbb plane
//   [10368,12928) wl1: conv1 A-frags (10 chunks x 64 lanes x 4 dw)
//   [12928,15488) wl2: conv2 A-frags
// swizzle bofs(y,x)=((y*36+x)*16)^((x&8)<<1)  (bijective, R9-proven).
// Conv as MFMA 16x16x32 with ROW-REUSE:
//   chunk (ty,txh): A[16 rows=(dx*8+oc)][32 k=(tx=4*txh+tg, ch)] frag
//   ONE B-read = pixel bundles at row pr, x=2*col+tx  feeds MFMAs for output
//   rows g = pr-ty (0<=g<4).  (tx=6,7 slots have zero A-weights; their reads
//   land <=32B past the plane, inside the next LDS region -- garbage*0=0.)
//   D: col=lane&15=anchor, row=(lane>>4)*4+reg = dx*8+oc  (R9-verified)
// GroupNorm folded into conv2 (w2*sc at frag load, h-pads=-sh/sc,
// bias2' = b2 + S2*sh)  -- R9's proven scheme.
// WHY 512 threads: occupancy was pinned ~21.6% (2 blocks/CU) for all
// 256-thread variants R9-R15 regardless of LDS/VGPR; R7 (512-thr) hit 43.6%.
// Block residency looks capped at ~2/CU -> waves/CU scales with block size.
// 2 x 62.5 KB = 125 KB <= 160 KB -> 2 blocks co-resident = 16 waves/CU.
// launch_bounds(512,2) -> VGPR cap 128 (R8-verified spill-free regime);
// est live ~105 (acc 16 + frag 40 transient). Tripwire: FETCH_SIZE ~7 MB.

typedef _Float16 half8 __attribute__((ext_vector_type(8)));
typedef float f32x4 __attribute__((ext_vector_type(4)));

#define PLANE 5184              // dwords per pixel plane
#define HB    5184              // hbb dword offset
#define WL1   10368             // conv1 frag table dword offset
#define WL2   12928             // conv2 frag table dword offset
#define NLDS  15488             // total carved dwords

__device__ __forceinline__ unsigned pk2(float a, float b) {
    __half2 h = __float22half2_rn(make_float2(a, b));
    return *reinterpret_cast<unsigned*>(&h);
}
__device__ __forceinline__ float2 up2(unsigned u) {
    __half2 h = *reinterpret_cast<__half2*>(&u);
    return __half22float2(h);
}
__device__ __forceinline__ unsigned hmul2(unsigned a, unsigned b) {
    __half2 r = __hmul2(*reinterpret_cast<__half2*>(&a), *reinterpret_cast<__half2*>(&b));
    return *reinterpret_cast<unsigned*>(&r);
}
__device__ __forceinline__ float lrelu(float x) { return fmaxf(x, 0.01f * x); }
__device__ __forceinline__ int bofs(int y, int x) {
    return ((y * 36 + x) * 16) ^ ((x & 8) << 1);
}

// ---- prep: row-reuse A-fragments + tap-sum table (identical to R15) ----
// ws[0..2559]    : conv1 frags, chunk c=(ty*2+txh), lane l:
//   row=l&15 (dx=row>>3, oc=row&7), tg=l>>4, tx=4*txh+tg, kx=tx-dx
//   elem pair d = ch (2d,2d+1): w1[oc][ch][ty][kx], 0 if oc>=6 or kx not in [0,5)
// ws[2560..5119] : conv2 frags from w2 (0 if oc>=5, ch>=6)
// ws[5120..5149] : S2[oc][ch] = sum_tap w2[oc][ch][tap]  (f32)
__global__ void pack_weights(const float* __restrict__ w1,
                             const float* __restrict__ w2,
                             unsigned* __restrict__ ws)
{
    int t = blockIdx.x * 256 + threadIdx.x;
    if (t < 640) {
        int c = t >> 6, l = t & 63;
        int row = l & 15, tg = l >> 4;
        int dx = row >> 3, oc = row & 7;
        int ty = c >> 1, tx = 4 * (c & 1) + tg, kx = tx - dx;
        unsigned q[4];
        #pragma unroll
        for (int d = 0; d < 4; ++d) {
            float v0 = 0.f, v1 = 0.f;
            if (oc < 6 && kx >= 0 && kx < 5) {
                v0 = w1[(oc * 8 + 2 * d) * 25 + ty * 5 + kx];
                v1 = w1[(oc * 8 + 2 * d + 1) * 25 + ty * 5 + kx];
            }
            q[d] = pk2(v0, v1);
        }
        *(uint4*)&ws[t * 4] = make_uint4(q[0], q[1], q[2], q[3]);
    } else if (t < 1280) {
        int u = t - 640;
        int c = u >> 6, l = u & 63;
        int row = l & 15, tg = l >> 4;
        int dx = row >> 3, oc = row & 7;
        int ty = c >> 1, tx = 4 * (c & 1) + tg, kx = tx - dx;
        unsigned q[4];
        #pragma unroll
        for (int d = 0; d < 4; ++d) {
            float v0 = 0.f, v1 = 0.f;
            if (oc < 5 && kx >= 0 && kx < 5) {
                if (2 * d < 6)     v0 = w2[(oc * 6 + 2 * d) * 25 + ty * 5 + kx];
                if (2 * d + 1 < 6) v1 = w2[(oc * 6 + 2 * d + 1) * 25 + ty * 5 + kx];
            }
            q[d] = pk2(v0, v1);
        }
        *(uint4*)&ws[2560 + u * 4] = make_uint4(q[0], q[1], q[2], q[3]);
    } else if (t < 1310) {
        int idx = t - 1280;
        int oc = idx / 6, ch = idx % 6;
        float s = 0.f;
        for (int tap = 0; tap < 25; ++tap) s += w2[(oc * 6 + ch) * 25 + tap];
        ((float*)ws)[5120 + idx] = s;
    }
}

__global__ __launch_bounds__(512, 2)
void deq_kernel(const float* __restrict__ image,
                const unsigned* __restrict__ wks,
                const float* __restrict__ b1,
                const float* __restrict__ gam, const float* __restrict__ bet,
                const float* __restrict__ b2,
                const float* __restrict__ wh, const float* __restrict__ bh,
                float* __restrict__ out)
{
    __shared__ __align__(16) unsigned lds[NLDS];
    __shared__ float red[96];
    __shared__ float s2s[32];

    const int n    = blockIdx.x;
    const int tid  = threadIdx.x;
    const int lane = tid & 63;
    const int wid  = tid >> 6;          // 0..7: wave owns output rows wid*4..+3
    const int col  = lane & 15;         // anchor: pixels 2col, 2col+1
    const int tg   = lane >> 4;
    const int dxl  = tg >> 1;           // this lane's output dx
    const int sub  = tg & 1;            // 0: ch0-3, 1: ch4-7

    for (int p = tid; p < 2 * PLANE; p += 512) lds[p] = 0u;
    for (int p = tid; p < 2560; p += 512) {
        lds[WL1 + p] = wks[p];
        lds[WL2 + p] = wks[2560 + p];
    }
    if (tid < 30) s2s[tid] = ((const float*)wks)[5120 + tid];
    __syncthreads();

    {   // image -> zx bundle ch 5..7 (each thread one 1x2 strip)
        const int yy = tid >> 4, xx0 = (tid & 15) << 1;
        float2 i0 = *(const float2*)&image[(n * 3 + 0) * 1024 + yy * 32 + xx0];
        float2 i1 = *(const float2*)&image[(n * 3 + 1) * 1024 + yy * 32 + xx0];
        float2 i2 = *(const float2*)&image[(n * 3 + 2) * 1024 + yy * 32 + xx0];
        float a0[2] = {i0.x, i0.y};
        float a1[2] = {i1.x, i1.y};
        float a2[2] = {i2.x, i2.y};
        #pragma unroll
        for (int i = 0; i < 2; ++i) {
            unsigned* bp = (unsigned*)((char*)lds + bofs(yy + 2, xx0 + 2 + i));
            bp[2] = pk2(0.f, a0[i]);
            bp[3] = pk2(a1[i], a2[i]);
        }
    }

    // per-lane x-offsets for the two tx-halves: x = 2*col + 4*txh + tg
    int sx2[2];
    #pragma unroll
    for (int txh = 0; txh < 2; ++txh) {
        int x = 2 * col + 4 * txh + tg;
        sx2[txh] = (x * 16) ^ ((x & 8) << 1);
    }

    float b1q[4], b2q[4];
    #pragma unroll
    for (int r = 0; r < 4; ++r) {
        int oc = (tg * 4 + r) & 7;
        b1q[r] = (oc < 6) ? b1[oc] : 0.f;
        b2q[r] = (oc < 5) ? b2[oc] : 0.f;
    }
    const f32x4 ai1 = {b1q[0], b1q[1], b1q[2], b1q[3]};

    __syncthreads();

    const char* zb  = (const char*)lds;
    const char* hbB = (const char*)lds + HB * 4;
    const int ay0 = wid << 2;           // wave owns output rows ay0..ay0+3
    const int wlo = lane << 2;          // lane's frag dword base within a chunk

    #pragma unroll 1
    for (int it = 0; it < 30; ++it) {
        // ========== conv1 (row-reuse: 16 B-reads, 40 MFMA per wave) ==========
        uint4 f1[10];
        #pragma unroll
        for (int c = 0; c < 10; ++c)
            f1[c] = *(const uint4*)&lds[WL1 + c * 256 + wlo];

        f32x4 acc[4];
        #pragma unroll
        for (int g = 0; g < 4; ++g) acc[g] = ai1;

        #pragma unroll
        for (int pr = 0; pr < 8; ++pr) {
            const char* rowp = zb + (ay0 + pr) * 576;
            #pragma unroll
            for (int txh = 0; txh < 2; ++txh) {
                half8 pv = *(const half8*)(rowp + sx2[txh]);
                #pragma unroll
                for (int ty = 0; ty < 5; ++ty) {
                    const int g = pr - ty;
                    if (g >= 0 && g < 4)
                        acc[g] = __builtin_amdgcn_mfma_f32_16x16x32_f16(
                            __builtin_bit_cast(half8, f1[ty * 2 + txh]), pv, acc[g], 0, 0, 0);
                }
            }
        }

        // ---- leaky + h write + GN partial stats ----
        float ps_lo = 0.f, ps_hi = 0.f, pq_lo = 0.f, pq_hi = 0.f;
        #pragma unroll
        for (int g = 0; g < 4; ++g) {
            float h0 = lrelu(acc[g][0]), h1 = lrelu(acc[g][1]);
            float h2 = lrelu(acc[g][2]), h3 = lrelu(acc[g][3]);
            ps_lo += h0 + h1;  pq_lo = fmaf(h0, h0, fmaf(h1, h1, pq_lo));
            ps_hi += h2 + h3;  pq_hi = fmaf(h2, h2, fmaf(h3, h3, pq_hi));
            char* wp = (char*)lds + HB * 4 + bofs(ay0 + g + 2, 2 * col + dxl + 2) + sub * 8;
            *(uint2*)wp = make_uint2(pk2(h0, h1), pk2(h2, h3));
        }

        // GN stats reduce: anchors (xor 1..8) then dx halves (xor 32)
        #pragma unroll
        for (int m = 1; m <= 8; m <<= 1) {
            ps_lo += __shfl_xor(ps_lo, m); ps_hi += __shfl_xor(ps_hi, m);
            pq_lo += __shfl_xor(pq_lo, m); pq_hi += __shfl_xor(pq_hi, m);
        }
        ps_lo += __shfl_xor(ps_lo, 32); ps_hi += __shfl_xor(ps_hi, 32);
        pq_lo += __shfl_xor(pq_lo, 32); pq_hi += __shfl_xor(pq_hi, 32);
        if (lane == 0)  { red[wid * 8 + 0] = ps_lo; red[wid * 8 + 1] = ps_hi;
                          red[wid * 8 + 4] = pq_lo; red[wid * 8 + 5] = pq_hi; }
        if (lane == 16) { red[wid * 8 + 2] = ps_lo; red[wid * 8 + 6] = pq_lo; }
        __syncthreads();                               // B1

        // ---- fold GN into conv2 operands ----
        float scv[6], shv[6];
        #pragma unroll
        for (int g3 = 0; g3 < 3; ++g3) {
            float s = 0.f, q = 0.f;
            #pragma unroll
            for (int w = 0; w < 8; ++w) { s += red[w * 8 + g3]; q += red[w * 8 + 4 + g3]; }
            float mean = s * (1.f / 2048.f);
            float var  = q * (1.f / 2048.f) - mean * mean;
            float inv  = rsqrtf(var + 1e-5f);
            #pragma unroll
            for (int k = 0; k < 2; ++k) {
                int c = 2 * g3 + k;
                scv[c] = inv * gam[c];
                shv[c] = bet[c] - mean * scv[c];
            }
        }
        f32x4 ai2;
        #pragma unroll
        for (int r = 0; r < 4; ++r) {
            int ocr = (tg * 4 + r) & 7;
            int base = (ocr < 5) ? ocr * 6 : 0;
            float db = 0.f;
            #pragma unroll
            for (int ch = 0; ch < 6; ++ch) db = fmaf(s2s[base + ch], shv[ch], db);
            ai2[r] = b2q[r] + ((ocr < 5) ? db : 0.f);
        }
        unsigned sp0 = pk2(scv[0], scv[1]), sp1 = pk2(scv[2], scv[3]), sp2 = pk2(scv[4], scv[5]);
        // h pads <- -sh/sc
        {
            float ph[6];
            #pragma unroll
            for (int c = 0; c < 6; ++c) {
                float rs = (fabsf(scv[c]) > 1e-20f) ? 1.f / scv[c] : 0.f;
                ph[c] = -shv[c] * rs;
            }
            uint4 padq = make_uint4(pk2(ph[0], ph[1]), pk2(ph[2], ph[3]), pk2(ph[4], ph[5]), 0u);
            if (tid < 272) {
                int row, cc;
                if (tid < 72)       { row = tid / 36;             cc = tid % 36; }
                else if (tid < 144) { row = 34 + (tid - 72) / 36; cc = (tid - 72) % 36; }
                else {
                    int q4 = tid - 144;
                    row = 2 + (q4 >> 2);
                    int c4 = q4 & 3;
                    cc = (c4 < 2) ? c4 : c4 + 32;
                }
                *(uint4*)((char*)lds + HB * 4 + bofs(row, cc)) = padq;
            }
        }
        __syncthreads();                               // B2

        // ====== conv2 (row-reuse; frags from LDS, scaled at load) ======
        uint4 f2[10];
        #pragma unroll
        for (int c = 0; c < 10; ++c) {
            uint4 wr = *(const uint4*)&lds[WL2 + c * 256 + wlo];
            f2[c].x = hmul2(wr.x, sp0);
            f2[c].y = hmul2(wr.y, sp1);
            f2[c].z = hmul2(wr.z, sp2);
            f2[c].w = 0u;
        }
        #pragma unroll
        for (int g = 0; g < 4; ++g) acc[g] = ai2;

        #pragma unroll
        for (int pr = 0; pr < 8; ++pr) {
            const char* rowp = hbB + (ay0 + pr) * 576;
            #pragma unroll
            for (int txh = 0; txh < 2; ++txh) {
                half8 pv = *(const half8*)(rowp + sx2[txh]);
                #pragma unroll
                for (int ty = 0; ty < 5; ++ty) {
                    const int g = pr - ty;
                    if (g >= 0 && g < 4)
                        acc[g] = __builtin_amdgcn_mfma_f32_16x16x32_f16(
                            __builtin_bit_cast(half8, f2[ty * 2 + txh]), pv, acc[g], 0, 0, 0);
                }
            }
        }

        // ---- leaky + damped z RMW ----
        #pragma unroll
        for (int g = 0; g < 4; ++g) {
            char* zp = (char*)lds + bofs(ay0 + g + 2, 2 * col + dxl + 2);
            if (sub == 0) {       // z0..z3: b64 RMW
                uint2 zo = *(uint2*)zp;
                float2 za = up2(zo.x), zc = up2(zo.y);
                float z0 = 0.5f * za.x + 0.5f * lrelu(acc[g][0]);
                float z1 = 0.5f * za.y + 0.5f * lrelu(acc[g][1]);
                float z2 = 0.5f * zc.x + 0.5f * lrelu(acc[g][2]);
                float z3 = 0.5f * zc.y + 0.5f * lrelu(acc[g][3]);
                *(uint2*)zp = make_uint2(pk2(z0, z1), pk2(z2, z3));
            } else {              // z4: u16 RMW (img0 in hi half untouched)
                _Float16* pz = (_Float16*)(zp + 8);
                float z4 = 0.5f * (float)pz[0] + 0.5f * lrelu(acc[g][0]);
                pz[0] = (_Float16)z4;
            }
        }
        __syncthreads();                               // B3
    }

    // ================= head: out[o] = <z, wh[o]> + bh[o] =================
    {
        const int yy = tid >> 4, xx0 = (tid & 15) << 1;
        float zf[5][2];
        #pragma unroll
        for (int i = 0; i < 2; ++i) {
            const unsigned* bp = (const unsigned*)((const char*)lds + bofs(yy + 2, xx0 + 2 + i));
            float2 f0 = up2(bp[0]), f1 = up2(bp[1]), f2 = up2(bp[2]);
            zf[0][i] = f0.x; zf[1][i] = f0.y; zf[2][i] = f1.x; zf[3][i] = f1.y; zf[4][i] = f2.x;
        }
        float ho[10];
        #pragma unroll
        for (int o = 0; o < 10; ++o) ho[o] = 0.f;
        #pragma unroll
        for (int c = 0; c < 5; ++c) {
            #pragma unroll
            for (int o = 0; o < 10; ++o) {
                float2 wv = *(const float2*)&wh[(o * 5 + c) * 1024 + yy * 32 + xx0];
                ho[o] = fmaf(zf[c][0], wv.x, ho[o]);
                ho[o] = fmaf(zf[c][1], wv.y, ho[o]);
            }
        }
        #pragma unroll
        for (int m = 1; m < 64; m <<= 1) {
            #pragma unroll
            for (int o = 0; o < 10; ++o) ho[o] += __shfl_xor(ho[o], m);
        }
        if (lane == 0) {
            #pragma unroll
            for (int o = 0; o < 10; ++o) red[wid * 10 + o] = ho[o];
        }
    }
    __syncthreads();
    if (tid < 10) {
        float s = bh[tid];
        #pragma unroll
        for (int w = 0; w < 8; ++w) s += red[w * 10 + tid];
        out[n * 10 + tid] = s;
    }
}

extern "C" void kernel_launch(void* const* d_in, const int* in_sizes, int n_in,
                              void* d_out, int out_size, void* d_ws, size_t ws_size,
                              hipStream_t stream) {
    const float* image = (const float*)d_in[0];
    const float* w1    = (const float*)d_in[1];
    const float* b1    = (const float*)d_in[2];
    const float* gam   = (const float*)d_in[3];
    const float* bet   = (const float*)d_in[4];
    const float* w2    = (const float*)d_in[5];
    const float* b2    = (const float*)d_in[6];
    const float* wh    = (const float*)d_in[7];
    const float* bh    = (const float*)d_in[8];
    float* out = (float*)d_out;
    unsigned* ws = (unsigned*)d_ws;

    pack_weights<<<6, 256, 0, stream>>>(w1, w2, ws);

    const int N = in_sizes[0] / (3 * 32 * 32);   // 1024 images
    deq_kernel<<<N, 512, 0, stream>>>(image, ws, b1, gam, bet, b2, wh, bh, out);
}

// Round 17
// 382.118 us; speedup vs baseline: 1.0826x; 1.0826x over previous
//
#include <hip/hip_runtime.h>
#include <hip/hip_fp16.h>

// DEQ classifier, dx-packed 16x16x32 MFMA with ROW-REUSE, wave0-delegated fold.
// One block per image (1024 x 256 threads, 4 waves; wave owns 8 output rows,
// acc[8], row-reuse over its 12 pixel rows). LDS carve:
//   [0,5184)      zxb plane  (36x36 bundles of 8-ch f16, 16 B each)
//   [5184,10368)  hbb plane
//   [10368,12928) wl1: conv1 A-frags (10 chunks x 64 lanes x 4 dw)
//   [12928,15488) wl2: conv2 A-frags (raw)
//   [15488,18048) f2s: conv2 A-frags scaled by this iter's GN sc (wave0-built)
// swizzle bofs(y,x)=((y*36+x)*16)^((x&8)<<1)  (bijective, R9-proven).
// Conv as MFMA 16x16x32 with ROW-REUSE (R15-proven):
//   chunk (ty,txh): A[16 rows=(dx*8+oc)][32 k=(tx=4*txh+tg, ch)] frag
//   ONE B-read at pixel row pr feeds MFMAs for output rows g=pr-ty (0<=g<8).
//   (tx=6,7 slots have zero A-weights; reads land <=32B past the plane,
//    inside the next LDS region -- garbage*0=0.)
//   D: col=lane&15=anchor, row=(lane>>4)*4+reg = dx*8+oc
// GN fold DELEGATED TO WAVE0 (between B1/B2): computes sc/sh once, pre-scales
// f2s table (10 reads+30 hmul2+10 writes), writes bias2s[16] = b2 + S2*sh,
// writes 272 h-pad bundles (-sh/sc). Other waves skip the fold entirely ->
// saves ~48 LDS b32 reads + ~140 VALU ops per thread per iter (the R15 model
// showed the redundant fold was ~40% of the dominant LDS-pipe load).
// WHY NOT 512 threads: R16 proved occupancy isn't the bound (42.5% occ,
// SLOWER) -- total work per CU is; 256-thr minimizes duplicated work.
// launch_bounds(256,2) -> VGPR cap 128; est ~100. Tripwire: FETCH ~7 MB.

typedef _Float16 half8 __attribute__((ext_vector_type(8)));
typedef float f32x4 __attribute__((ext_vector_type(4)));

#define PLANE 5184              // dwords per pixel plane
#define HB    5184              // hbb dword offset
#define WL1   10368             // conv1 frag table dword offset
#define WL2   12928             // conv2 raw frag table dword offset
#define F2S   15488             // conv2 scaled frag table dword offset
#define NLDS  18048             // total carved dwords

__device__ __forceinline__ unsigned pk2(float a, float b) {
    __half2 h = __float22half2_rn(make_float2(a, b));
    return *reinterpret_cast<unsigned*>(&h);
}
__device__ __forceinline__ float2 up2(unsigned u) {
    __half2 h = *reinterpret_cast<__half2*>(&u);
    return __half22float2(h);
}
__device__ __forceinline__ unsigned hmul2(unsigned a, unsigned b) {
    __half2 r = __hmul2(*reinterpret_cast<__half2*>(&a), *reinterpret_cast<__half2*>(&b));
    return *reinterpret_cast<unsigned*>(&r);
}
__device__ __forceinline__ float lrelu(float x) { return fmaxf(x, 0.01f * x); }
__device__ __forceinline__ int bofs(int y, int x) {
    return ((y * 36 + x) * 16) ^ ((x & 8) << 1);
}

// ---- prep: row-reuse A-fragments + tap-sum table (identical to R15) ----
// ws[0..2559]    : conv1 frags, chunk c=(ty*2+txh), lane l:
//   row=l&15 (dx=row>>3, oc=row&7), tg=l>>4, tx=4*txh+tg, kx=tx-dx
//   elem pair d = ch (2d,2d+1): w1[oc][ch][ty][kx], 0 if oc>=6 or kx not in [0,5)
// ws[2560..5119] : conv2 frags from w2 (0 if oc>=5, ch>=6)
// ws[5120..5149] : S2[oc][ch] = sum_tap w2[oc][ch][tap]  (f32)
__global__ void pack_weights(const float* __restrict__ w1,
                             const float* __restrict__ w2,
                             unsigned* __restrict__ ws)
{
    int t = blockIdx.x * 256 + threadIdx.x;
    if (t < 640) {
        int c = t >> 6, l = t & 63;
        int row = l & 15, tg = l >> 4;
        int dx = row >> 3, oc = row & 7;
        int ty = c >> 1, tx = 4 * (c & 1) + tg, kx = tx - dx;
        unsigned q[4];
        #pragma unroll
        for (int d = 0; d < 4; ++d) {
            float v0 = 0.f, v1 = 0.f;
            if (oc < 6 && kx >= 0 && kx < 5) {
                v0 = w1[(oc * 8 + 2 * d) * 25 + ty * 5 + kx];
                v1 = w1[(oc * 8 + 2 * d + 1) * 25 + ty * 5 + kx];
            }
            q[d] = pk2(v0, v1);
        }
        *(uint4*)&ws[t * 4] = make_uint4(q[0], q[1], q[2], q[3]);
    } else if (t < 1280) {
        int u = t - 640;
        int c = u >> 6, l = u & 63;
        int row = l & 15, tg = l >> 4;
        int dx = row >> 3, oc = row & 7;
        int ty = c >> 1, tx = 4 * (c & 1) + tg, kx = tx - dx;
        unsigned q[4];
        #pragma unroll
        for (int d = 0; d < 4; ++d) {
            float v0 = 0.f, v1 = 0.f;
            if (oc < 5 && kx >= 0 && kx < 5) {
                if (2 * d < 6)     v0 = w2[(oc * 6 + 2 * d) * 25 + ty * 5 + kx];
                if (2 * d + 1 < 6) v1 = w2[(oc * 6 + 2 * d + 1) * 25 + ty * 5 + kx];
            }
            q[d] = pk2(v0, v1);
        }
        *(uint4*)&ws[2560 + u * 4] = make_uint4(q[0], q[1], q[2], q[3]);
    } else if (t < 1310) {
        int idx = t - 1280;
        int oc = idx / 6, ch = idx % 6;
        float s = 0.f;
        for (int tap = 0; tap < 25; ++tap) s += w2[(oc * 6 + ch) * 25 + tap];
        ((float*)ws)[5120 + idx] = s;
    }
}

__global__ __launch_bounds__(256, 2)
void deq_kernel(const float* __restrict__ image,
                const unsigned* __restrict__ wks,
                const float* __restrict__ b1,
                const float* __restrict__ gam, const float* __restrict__ bet,
                const float* __restrict__ b2,
                const float* __restrict__ wh, const float* __restrict__ bh,
                float* __restrict__ out)
{
    __shared__ __align__(16) unsigned lds[NLDS];
    __shared__ float red[48];
    __shared__ float s2s[32];
    __shared__ float bias2s[16];

    const int n    = blockIdx.x;
    const int tid  = threadIdx.x;
    const int lane = tid & 63;
    const int wid  = tid >> 6;          // 0..3: wave owns output rows wid*8..+7
    const int col  = lane & 15;         // anchor: pixels 2col, 2col+1
    const int tg   = lane >> 4;
    const int dxl  = tg >> 1;           // this lane's output dx
    const int sub  = tg & 1;            // 0: ch0-3, 1: ch4-7

    for (int p = tid; p < 2 * PLANE; p += 256) lds[p] = 0u;
    for (int p = tid; p < 2560; p += 256) {
        lds[WL1 + p] = wks[p];
        lds[WL2 + p] = wks[2560 + p];
    }
    if (tid < 30) s2s[tid] = ((const float*)wks)[5120 + tid];
    __syncthreads();

    {   // image -> zx bundle ch 5..7 (each thread one 1x4 strip)
        const int yy = tid >> 3, xx0 = (tid & 7) << 2;
        float4 i0 = *(const float4*)&image[(n * 3 + 0) * 1024 + yy * 32 + xx0];
        float4 i1 = *(const float4*)&image[(n * 3 + 1) * 1024 + yy * 32 + xx0];
        float4 i2 = *(const float4*)&image[(n * 3 + 2) * 1024 + yy * 32 + xx0];
        float a0[4] = {i0.x, i0.y, i0.z, i0.w};
        float a1[4] = {i1.x, i1.y, i1.z, i1.w};
        float a2[4] = {i2.x, i2.y, i2.z, i2.w};
        #pragma unroll
        for (int i = 0; i < 4; ++i) {
            unsigned* bp = (unsigned*)((char*)lds + bofs(yy + 2, xx0 + 2 + i));
            bp[2] = pk2(0.f, a0[i]);
            bp[3] = pk2(a1[i], a2[i]);
        }
    }

    // per-lane x-offsets for the two tx-halves: x = 2*col + 4*txh + tg
    int sx2[2];
    #pragma unroll
    for (int txh = 0; txh < 2; ++txh) {
        int x = 2 * col + 4 * txh + tg;
        sx2[txh] = (x * 16) ^ ((x & 8) << 1);
    }

    float b1q[4];
    #pragma unroll
    for (int r = 0; r < 4; ++r) {
        int oc = (tg * 4 + r) & 7;
        b1q[r] = (oc < 6) ? b1[oc] : 0.f;
    }
    const f32x4 ai1 = {b1q[0], b1q[1], b1q[2], b1q[3]};

    // wave0 lanes 0..3 act as "tg" for the bias2 fold; preload their b2
    float b2w[4] = {0.f, 0.f, 0.f, 0.f};
    if (wid == 0 && lane < 4) {
        #pragma unroll
        for (int r = 0; r < 4; ++r) {
            int ocr = (lane * 4 + r) & 7;
            b2w[r] = (ocr < 5) ? b2[ocr] : 0.f;
        }
    }

    __syncthreads();

    const char* zb  = (const char*)lds;
    const char* hbB = (const char*)lds + HB * 4;
    const int ay0 = wid << 3;           // wave owns output rows ay0..ay0+7
    const int wlo = lane << 2;          // lane's frag dword base within a chunk

    #pragma unroll 1
    for (int it = 0; it < 30; ++it) {
        // ================= conv1 (row-reuse: 24 B-reads, 80 MFMA) =================
        uint4 f1[10];
        #pragma unroll
        for (int c = 0; c < 10; ++c)
            f1[c] = *(const uint4*)&lds[WL1 + c * 256 + wlo];

        f32x4 acc[8];
        #pragma unroll
        for (int g = 0; g < 8; ++g) acc[g] = ai1;

        #pragma unroll
        for (int pr = 0; pr < 12; ++pr) {
            const char* rowp = zb + (ay0 + pr) * 576;
            #pragma unroll
            for (int txh = 0; txh < 2; ++txh) {
                half8 pv = *(const half8*)(rowp + sx2[txh]);
                #pragma unroll
                for (int ty = 0; ty < 5; ++ty) {
                    const int g = pr - ty;
                    if (g >= 0 && g < 8)
                        acc[g] = __builtin_amdgcn_mfma_f32_16x16x32_f16(
                            __builtin_bit_cast(half8, f1[ty * 2 + txh]), pv, acc[g], 0, 0, 0);
                }
            }
        }

        // ---- leaky + h write + GN partial stats ----
        float ps_lo = 0.f, ps_hi = 0.f, pq_lo = 0.f, pq_hi = 0.f;
        #pragma unroll
        for (int g = 0; g < 8; ++g) {
            float h0 = lrelu(acc[g][0]), h1 = lrelu(acc[g][1]);
            float h2 = lrelu(acc[g][2]), h3 = lrelu(acc[g][3]);
            ps_lo += h0 + h1;  pq_lo = fmaf(h0, h0, fmaf(h1, h1, pq_lo));
            ps_hi += h2 + h3;  pq_hi = fmaf(h2, h2, fmaf(h3, h3, pq_hi));
            char* wp = (char*)lds + HB * 4 + bofs(ay0 + g + 2, 2 * col + dxl + 2) + sub * 8;
            *(uint2*)wp = make_uint2(pk2(h0, h1), pk2(h2, h3));
        }

        // GN stats reduce: anchors (xor 1..8) then dx halves (xor 32)
        #pragma unroll
        for (int m = 1; m <= 8; m <<= 1) {
            ps_lo += __shfl_xor(ps_lo, m); ps_hi += __shfl_xor(ps_hi, m);
            pq_lo += __shfl_xor(pq_lo, m); pq_hi += __shfl_xor(pq_hi, m);
        }
        ps_lo += __shfl_xor(ps_lo, 32); ps_hi += __shfl_xor(ps_hi, 32);
        pq_lo += __shfl_xor(pq_lo, 32); pq_hi += __shfl_xor(pq_hi, 32);
        if (lane == 0)  { red[wid * 8 + 0] = ps_lo; red[wid * 8 + 1] = ps_hi;
                          red[wid * 8 + 4] = pq_lo; red[wid * 8 + 5] = pq_hi; }
        if (lane == 16) { red[wid * 8 + 2] = ps_lo; red[wid * 8 + 6] = pq_lo; }
        __syncthreads();                               // B1

        // ====== wave0-only: GN fold -> f2s table, bias2s, h-pads ======
        if (wid == 0) {
            float scv[6], shv[6];
            #pragma unroll
            for (int g3 = 0; g3 < 3; ++g3) {
                float s = 0.f, q = 0.f;
                #pragma unroll
                for (int w = 0; w < 4; ++w) { s += red[w * 8 + g3]; q += red[w * 8 + 4 + g3]; }
                float mean = s * (1.f / 2048.f);
                float var  = q * (1.f / 2048.f) - mean * mean;
                float inv  = rsqrtf(var + 1e-5f);
                #pragma unroll
                for (int k = 0; k < 2; ++k) {
                    int c = 2 * g3 + k;
                    scv[c] = inv * gam[c];
                    shv[c] = bet[c] - mean * scv[c];
                }
            }
            unsigned sp0 = pk2(scv[0], scv[1]), sp1 = pk2(scv[2], scv[3]), sp2 = pk2(scv[4], scv[5]);
            // pre-scale conv2 frag table (this lane's slot in all 10 chunks)
            #pragma unroll
            for (int c = 0; c < 10; ++c) {
                uint4 wr = *(const uint4*)&lds[WL2 + c * 256 + wlo];
                uint4 wsc;
                wsc.x = hmul2(wr.x, sp0);
                wsc.y = hmul2(wr.y, sp1);
                wsc.z = hmul2(wr.z, sp2);
                wsc.w = 0u;
                *(uint4*)&lds[F2S + c * 256 + wlo] = wsc;
            }
            // bias2' = b2 + S2*sh for the 16 (tg,r) slots (lanes 0..3 = tg)
            if (lane < 4) {
                #pragma unroll
                for (int r = 0; r < 4; ++r) {
                    int ocr = (lane * 4 + r) & 7;
                    float v = 0.f;
                    if (ocr < 5) {
                        v = b2w[r];
                        #pragma unroll
                        for (int ch = 0; ch < 6; ++ch)
                            v = fmaf(s2s[ocr * 6 + ch], shv[ch], v);
                    }
                    bias2s[lane * 4 + r] = v;
                }
            }
            // h pads <- -sh/sc
            float ph[6];
            #pragma unroll
            for (int c = 0; c < 6; ++c) {
                float rs = (fabsf(scv[c]) > 1e-20f) ? 1.f / scv[c] : 0.f;
                ph[c] = -shv[c] * rs;
            }
            uint4 padq = make_uint4(pk2(ph[0], ph[1]), pk2(ph[2], ph[3]), pk2(ph[4], ph[5]), 0u);
            #pragma unroll 1
            for (int t = lane; t < 272; t += 64) {
                int row, cc;
                if (t < 72)       { row = t / 36;             cc = t % 36; }
                else if (t < 144) { row = 34 + (t - 72) / 36; cc = (t - 72) % 36; }
                else {
                    int q4 = t - 144;
                    row = 2 + (q4 >> 2);
                    int c4 = q4 & 3;
                    cc = (c4 < 2) ? c4 : c4 + 32;
                }
                *(uint4*)((char*)lds + HB * 4 + bofs(row, cc)) = padq;
            }
        }
        __syncthreads();                               // B2

        // ====== conv2 (row-reuse; PRE-SCALED frags + folded bias from LDS) ======
        f32x4 ai2 = {bias2s[tg * 4 + 0], bias2s[tg * 4 + 1],
                     bias2s[tg * 4 + 2], bias2s[tg * 4 + 3]};
        uint4 f2[10];
        #pragma unroll
        for (int c = 0; c < 10; ++c)
            f2[c] = *(const uint4*)&lds[F2S + c * 256 + wlo];

        #pragma unroll
        for (int g = 0; g < 8; ++g) acc[g] = ai2;

        #pragma unroll
        for (int pr = 0; pr < 12; ++pr) {
            const char* rowp = hbB + (ay0 + pr) * 576;
            #pragma unroll
            for (int txh = 0; txh < 2; ++txh) {
                half8 pv = *(const half8*)(rowp + sx2[txh]);
                #pragma unroll
                for (int ty = 0; ty < 5; ++ty) {
                    const int g = pr - ty;
                    if (g >= 0 && g < 8)
                        acc[g] = __builtin_amdgcn_mfma_f32_16x16x32_f16(
                            __builtin_bit_cast(half8, f2[ty * 2 + txh]), pv, acc[g], 0, 0, 0);
                }
            }
        }

        // ---- leaky + damped z RMW ----
        #pragma unroll
        for (int g = 0; g < 8; ++g) {
            char* zp = (char*)lds + bofs(ay0 + g + 2, 2 * col + dxl + 2);
            if (sub == 0) {       // z0..z3: b64 RMW
                uint2 zo = *(uint2*)zp;
                float2 za = up2(zo.x), zc = up2(zo.y);
                float z0 = 0.5f * za.x + 0.5f * lrelu(acc[g][0]);
                float z1 = 0.5f * za.y + 0.5f * lrelu(acc[g][1]);
                float z2 = 0.5f * zc.x + 0.5f * lrelu(acc[g][2]);
                float z3 = 0.5f * zc.y + 0.5f * lrelu(acc[g][3]);
                *(uint2*)zp = make_uint2(pk2(z0, z1), pk2(z2, z3));
            } else {              // z4: u16 RMW (img0 in hi half untouched)
                _Float16* pz = (_Float16*)(zp + 8);
                float z4 = 0.5f * (float)pz[0] + 0.5f * lrelu(acc[g][0]);
                pz[0] = (_Float16)z4;
            }
        }
        __syncthreads();                               // B3
    }

    // ================= head: out[o] = <z, wh[o]> + bh[o] =================
    {
        const int yy = tid >> 3, xx0 = (tid & 7) << 2;
        float zf[5][4];
        #pragma unroll
        for (int i = 0; i < 4; ++i) {
            const unsigned* bp = (const unsigned*)((const char*)lds + bofs(yy + 2, xx0 + 2 + i));
            float2 f0 = up2(bp[0]), f1 = up2(bp[1]), f2 = up2(bp[2]);
            zf[0][i] = f0.x; zf[1][i] = f0.y; zf[2][i] = f1.x; zf[3][i] = f1.y; zf[4][i] = f2.x;
        }
        float ho[10];
        #pragma unroll
        for (int o = 0; o < 10; ++o) ho[o] = 0.f;
        #pragma unroll
        for (int c = 0; c < 5; ++c) {
            #pragma unroll
            for (int o = 0; o < 10; ++o) {
                float4 wv = *(const float4*)&wh[(o * 5 + c) * 1024 + yy * 32 + xx0];
                ho[o] = fmaf(zf[c][0], wv.x, ho[o]);
                ho[o] = fmaf(zf[c][1], wv.y, ho[o]);
                ho[o] = fmaf(zf[c][2], wv.z, ho[o]);
                ho[o] = fmaf(zf[c][3], wv.w, ho[o]);
            }
        }
        #pragma unroll
        for (int m = 1; m < 64; m <<= 1) {
            #pragma unroll
            for (int o = 0; o < 10; ++o) ho[o] += __shfl_xor(ho[o], m);
        }
        if (lane == 0) {
            #pragma unroll
            for (int o = 0; o < 10; ++o) red[wid * 10 + o] = ho[o];
        }
    }
    __syncthreads();
    if (tid < 10)
        out[n * 10 + tid] = red[tid] + red[10 + tid] + red[20 + tid] + red[30 + tid] + bh[tid];
}

extern "C" void kernel_launch(void* const* d_in, const int* in_sizes, int n_in,
                              void* d_out, int out_size, void* d_ws, size_t ws_size,
                              hipStream_t stream) {
    const float* image = (const float*)d_in[0];
    const float* w1    = (const float*)d_in[1];
    const float* b1    = (const float*)d_in[2];
    const float* gam   = (const float*)d_in[3];
    const float* bet   = (const float*)d_in[4];
    const float* w2    = (const float*)d_in[5];
    const float* b2    = (const float*)d_in[6];
    const float* wh    = (const float*)d_in[7];
    const float* bh    = (const float*)d_in[8];
    float* out = (float*)d_out;
    unsigned* ws = (unsigned*)d_ws;

    pack_weights<<<6, 256, 0, stream>>>(w1, w2, ws);

    const int N = in_sizes[0] / (3 * 32 * 32);   // 1024 images
    deq_kernel<<<N, 256, 0, stream>>>(image, ws, b1, gam, bet, b2, wh, bh, out);
}

// Round 19
// 309.648 us; speedup vs baseline: 1.3359x; 1.2340x over previous
//
#include <hip/hip_runtime.h>
#include <hip/hip_fp16.h>

// DEQ classifier, dx-packed 16x16x32 MFMA, row-reuse, NORMALIZED-H scheme.
// One block per image (1024 x 256 threads, 4 waves; wave owns 8 output rows,
// acc[8] held across the GN fold). LDS: ONE combined 71-row x 36-bundle
// buffer (8-ch f16 pixel bundles, 16 B), swizzle bofs(r,x)=((r*36+x)*16)^((x&8)<<1):
//   rows 0..35  : zx plane (interior 2..33; ch z0..z4, img0..2)
//   rows 34..69 : h  plane (interior 36..67; ch h0..h5, 0, 0)
//   rows 34,35 SHARED pad; row 70 = GUARD ROW (never written, stays zero).
// R18 NaN post-mortem: row-reuse tx=6/7 reads overrun a row by <=2 bundles;
// on the LAST row they fell past the buffer into red[] whose float bits can
// be f16 NaN patterns -> MFMA 0*NaN = NaN. Guard row absorbs them (max
// overflow bundle 69*36+37 = 2521 < 71*36 = 2556). Interior-row overruns
// land in the next row's pad cols (always zero) -- safe.
// Conv as MFMA 16x16x32 with ROW-REUSE (R15-proven):
//   chunk (ty,txh): A[16 rows=(dx*8+oc)][32 k=(tx=4*txh+tg, ch)] frag
//   ONE B-read at pixel row pr feeds output rows g=pr-ty (0<=g<8).
//   D: col=lane&15=anchor, row=(lane>>4)*4+reg = dx*8+oc  (R9-verified)
// NORMALIZED-H: conv1 acc stays in regs across B1; after the cheap all-thread
// fold each thread writes h = sc*lrelu(acc)+sh. Conv2 uses RAW w2 frags +
// plain b2 bias: no pad-rewrite, no S2 table, no hmul2, exact zero pads.
// Both frag tables iteration-invariant -> loaded ONCE into VGPRs (80 regs).
// launch_bounds(256,1): no 128 cap; target ~150-170 VGPR -> 3 waves/SIMD ->
// 3 independent blocks/CU (R9-R17 plateau = barrier latency at 2 blocks).
// Tripwire: FETCH_SIZE must stay ~7 MB; spill shows as FETCH/WRITE blowup.

typedef _Float16 half8 __attribute__((ext_vector_type(8)));
typedef float f32x4 __attribute__((ext_vector_type(4)));

#define HOFF  34                  // h-plane row offset in combined buffer
#define NBUF  (71 * 36 * 4)       // 10224 dwords = 40896 B (incl. guard row)

__device__ __forceinline__ unsigned pk2(float a, float b) {
    __half2 h = __float22half2_rn(make_float2(a, b));
    return *reinterpret_cast<unsigned*>(&h);
}
__device__ __forceinline__ float2 up2(unsigned u) {
    __half2 h = *reinterpret_cast<__half2*>(&u);
    return __half22float2(h);
}
__device__ __forceinline__ float lrelu(float x) { return fmaxf(x, 0.01f * x); }
__device__ __forceinline__ int bofs(int r, int x) {
    return ((r * 36 + x) * 16) ^ ((x & 8) << 1);
}

// ---- prep: row-reuse A-fragments (R15 layout; no S2 table needed) ----
// ws[0..2559]    : conv1 frags, chunk c=(ty*2+txh), lane l:
//   row=l&15 (dx=row>>3, oc=row&7), tg=l>>4, tx=4*txh+tg, kx=tx-dx
//   elem pair d = ch (2d,2d+1): w1[oc][ch][ty][kx], 0 if oc>=6 or kx not in [0,5)
// ws[2560..5119] : conv2 frags from w2 (0 if oc>=5, ch>=6)
__global__ void pack_weights(const float* __restrict__ w1,
                             const float* __restrict__ w2,
                             unsigned* __restrict__ ws)
{
    int t = blockIdx.x * 256 + threadIdx.x;
    if (t < 640) {
        int c = t >> 6, l = t & 63;
        int row = l & 15, tg = l >> 4;
        int dx = row >> 3, oc = row & 7;
        int ty = c >> 1, tx = 4 * (c & 1) + tg, kx = tx - dx;
        unsigned q[4];
        #pragma unroll
        for (int d = 0; d < 4; ++d) {
            float v0 = 0.f, v1 = 0.f;
            if (oc < 6 && kx >= 0 && kx < 5) {
                v0 = w1[(oc * 8 + 2 * d) * 25 + ty * 5 + kx];
                v1 = w1[(oc * 8 + 2 * d + 1) * 25 + ty * 5 + kx];
            }
            q[d] = pk2(v0, v1);
        }
        *(uint4*)&ws[t * 4] = make_uint4(q[0], q[1], q[2], q[3]);
    } else if (t < 1280) {
        int u = t - 640;
        int c = u >> 6, l = u & 63;
        int row = l & 15, tg = l >> 4;
        int dx = row >> 3, oc = row & 7;
        int ty = c >> 1, tx = 4 * (c & 1) + tg, kx = tx - dx;
        unsigned q[4];
        #pragma unroll
        for (int d = 0; d < 4; ++d) {
            float v0 = 0.f, v1 = 0.f;
            if (oc < 5 && kx >= 0 && kx < 5) {
                if (2 * d < 6)     v0 = w2[(oc * 6 + 2 * d) * 25 + ty * 5 + kx];
                if (2 * d + 1 < 6) v1 = w2[(oc * 6 + 2 * d + 1) * 25 + ty * 5 + kx];
            }
            q[d] = pk2(v0, v1);
        }
        *(uint4*)&ws[2560 + u * 4] = make_uint4(q[0], q[1], q[2], q[3]);
    }
}

__global__ __launch_bounds__(256, 1)
void deq_kernel(const float* __restrict__ image,
                const unsigned* __restrict__ wks,
                const float* __restrict__ b1,
                const float* __restrict__ gam, const float* __restrict__ bet,
                const float* __restrict__ b2,
                const float* __restrict__ wh, const float* __restrict__ bh,
                float* __restrict__ out)
{
    __shared__ __align__(16) unsigned buf[NBUF];
    __shared__ float red[48];

    const int n    = blockIdx.x;
    const int tid  = threadIdx.x;
    const int lane = tid & 63;
    const int wid  = tid >> 6;          // 0..3: wave owns output rows wid*8..+7
    const int col  = lane & 15;         // anchor: pixels 2col, 2col+1
    const int tg   = lane >> 4;
    const int dxl  = tg >> 1;           // this lane's output dx
    const int sub  = tg & 1;            // 0: ch0-3, 1: ch4-7

    for (int p = tid; p < NBUF; p += 256) buf[p] = 0u;
    __syncthreads();

    {   // image -> zx bundle ch 5..7 (each thread one 1x4 strip)
        const int yy = tid >> 3, xx0 = (tid & 7) << 2;
        float4 i0 = *(const float4*)&image[(n * 3 + 0) * 1024 + yy * 32 + xx0];
        float4 i1 = *(const float4*)&image[(n * 3 + 1) * 1024 + yy * 32 + xx0];
        float4 i2 = *(const float4*)&image[(n * 3 + 2) * 1024 + yy * 32 + xx0];
        float a0[4] = {i0.x, i0.y, i0.z, i0.w};
        float a1[4] = {i1.x, i1.y, i1.z, i1.w};
        float a2[4] = {i2.x, i2.y, i2.z, i2.w};
        #pragma unroll
        for (int i = 0; i < 4; ++i) {
            unsigned* bp = (unsigned*)((char*)buf + bofs(yy + 2, xx0 + 2 + i));
            bp[2] = pk2(0.f, a0[i]);
            bp[3] = pk2(a1[i], a2[i]);
        }
    }

    // weight A-fragments: loaded ONCE into VGPRs (80 regs, iteration-invariant)
    uint4 f1[10], f2[10];
    #pragma unroll
    for (int c = 0; c < 10; ++c) {
        f1[c] = *(const uint4*)&wks[(c * 64 + lane) * 4];
        f2[c] = *(const uint4*)&wks[2560 + (c * 64 + lane) * 4];
    }

    // per-lane x-offsets for the two tx-halves: x = 2*col + 4*txh + tg
    int sx2[2];
    #pragma unroll
    for (int txh = 0; txh < 2; ++txh) {
        int x = 2 * col + 4 * txh + tg;
        sx2[txh] = (x * 16) ^ ((x & 8) << 1);
    }

    // per-thread channel constants (channels chb+0..3, chb = 4*(tg&1))
    const int chb = (tg & 1) * 4;
    float b1q[4], b2q[4], gq[4], bq[4];
    #pragma unroll
    for (int r = 0; r < 4; ++r) {
        int oc = chb + r;
        b1q[r] = (oc < 6) ? b1[oc] : 0.f;
        b2q[r] = (oc < 5) ? b2[oc] : 0.f;
        gq[r]  = (oc < 6) ? gam[oc] : 0.f;
        bq[r]  = (oc < 6) ? bet[oc] : 0.f;
    }
    const f32x4 ai1 = {b1q[0], b1q[1], b1q[2], b1q[3]};
    const f32x4 ai2 = {b2q[0], b2q[1], b2q[2], b2q[3]};

    __syncthreads();

    const char* zb = (const char*)buf;
    const int ay0 = wid << 3;           // wave owns output rows ay0..ay0+7
    const int hwp0 = bofs(0, 2 * col + dxl + 2) + sub * 8;   // h/z write x-part

    #pragma unroll 1
    for (int it = 0; it < 30; ++it) {
        // ================= conv1 (row-reuse: 24 B-reads, 80 MFMA) =================
        f32x4 acc[8];
        #pragma unroll
        for (int g = 0; g < 8; ++g) acc[g] = ai1;

        #pragma unroll
        for (int pr = 0; pr < 12; ++pr) {
            const char* rowp = zb + (ay0 + pr) * 576;
            #pragma unroll
            for (int txh = 0; txh < 2; ++txh) {
                half8 pv = *(const half8*)(rowp + sx2[txh]);
                #pragma unroll
                for (int ty = 0; ty < 5; ++ty) {
                    const int g = pr - ty;
                    if (g >= 0 && g < 8)
                        acc[g] = __builtin_amdgcn_mfma_f32_16x16x32_f16(
                            __builtin_bit_cast(half8, f1[ty * 2 + txh]), pv, acc[g], 0, 0, 0);
                }
            }
        }

        // ---- leaky (kept in regs) + GN partial stats ----
        float ps_lo = 0.f, ps_hi = 0.f, pq_lo = 0.f, pq_hi = 0.f;
        #pragma unroll
        for (int g = 0; g < 8; ++g) {
            float h0 = lrelu(acc[g][0]), h1 = lrelu(acc[g][1]);
            float h2 = lrelu(acc[g][2]), h3 = lrelu(acc[g][3]);
            acc[g][0] = h0; acc[g][1] = h1; acc[g][2] = h2; acc[g][3] = h3;
            ps_lo += h0 + h1;  pq_lo = fmaf(h0, h0, fmaf(h1, h1, pq_lo));
            ps_hi += h2 + h3;  pq_hi = fmaf(h2, h2, fmaf(h3, h3, pq_hi));
        }

        // GN stats reduce: anchors (xor 1..8) then dx halves (xor 32)
        #pragma unroll
        for (int m = 1; m <= 8; m <<= 1) {
            ps_lo += __shfl_xor(ps_lo, m); ps_hi += __shfl_xor(ps_hi, m);
            pq_lo += __shfl_xor(pq_lo, m); pq_hi += __shfl_xor(pq_hi, m);
        }
        ps_lo += __shfl_xor(ps_lo, 32); ps_hi += __shfl_xor(ps_hi, 32);
        pq_lo += __shfl_xor(pq_lo, 32); pq_hi += __shfl_xor(pq_hi, 32);
        if (lane == 0)  { red[wid * 8 + 0] = ps_lo; red[wid * 8 + 1] = ps_hi;
                          red[wid * 8 + 4] = pq_lo; red[wid * 8 + 5] = pq_hi; }
        if (lane == 16) { red[wid * 8 + 2] = ps_lo; red[wid * 8 + 6] = pq_lo; }
        __syncthreads();                               // B1

        // ---- cheap all-thread GN fold (acc still in regs) ----
        float invm[3], meanm[3];
        #pragma unroll
        for (int g3 = 0; g3 < 3; ++g3) {
            float s = 0.f, q = 0.f;
            #pragma unroll
            for (int w = 0; w < 4; ++w) { s += red[w * 8 + g3]; q += red[w * 8 + 4 + g3]; }
            float mean = s * (1.f / 2048.f);
            float var  = q * (1.f / 2048.f) - mean * mean;
            invm[g3]  = rsqrtf(var + 1e-5f);
            meanm[g3] = mean;
        }
        // this thread's 4 channels (chb..chb+3): sc = inv*gam, sh = bet - mean*sc
        float scq[4], shq[4];
        #pragma unroll
        for (int r = 0; r < 4; ++r) {
            int oc = chb + r;                    // 0..3 or 4..7
            float inv  = (oc < 6) ? invm[oc >> 1]  : 0.f;
            float mean = (oc < 6) ? meanm[oc >> 1] : 0.f;
            scq[r] = inv * gq[r];
            shq[r] = bq[r] - mean * scq[r];
        }

        // ---- write NORMALIZED h (zero pads stay exact forever) ----
        #pragma unroll
        for (int g = 0; g < 8; ++g) {
            float h0 = fmaf(acc[g][0], scq[0], shq[0]);
            float h1 = fmaf(acc[g][1], scq[1], shq[1]);
            float h2 = fmaf(acc[g][2], scq[2], shq[2]);
            float h3 = fmaf(acc[g][3], scq[3], shq[3]);
            char* wp = (char*)buf + (ay0 + g + 2 + HOFF) * 576 + hwp0;
            *(uint2*)wp = make_uint2(pk2(h0, h1), pk2(h2, h3));
        }
        __syncthreads();                               // B2

        // ====== conv2 (row-reuse; RAW w2 frags, plain b2 bias) ======
        #pragma unroll
        for (int g = 0; g < 8; ++g) acc[g] = ai2;

        #pragma unroll
        for (int pr = 0; pr < 12; ++pr) {
            const char* rowp = zb + (HOFF + ay0 + pr) * 576;
            #pragma unroll
            for (int txh = 0; txh < 2; ++txh) {
                half8 pv = *(const half8*)(rowp + sx2[txh]);
                #pragma unroll
                for (int ty = 0; ty < 5; ++ty) {
                    const int g = pr - ty;
                    if (g >= 0 && g < 8)
                        acc[g] = __builtin_amdgcn_mfma_f32_16x16x32_f16(
                            __builtin_bit_cast(half8, f2[ty * 2 + txh]), pv, acc[g], 0, 0, 0);
                }
            }
        }

        // ---- leaky + damped z RMW ----
        #pragma unroll
        for (int g = 0; g < 8; ++g) {
            char* zp = (char*)buf + bofs(ay0 + g + 2, 2 * col + dxl + 2);
            if (sub == 0) {       // z0..z3: b64 RMW
                uint2 zo = *(uint2*)zp;
                float2 za = up2(zo.x), zc = up2(zo.y);
                float z0 = 0.5f * za.x + 0.5f * lrelu(acc[g][0]);
                float z1 = 0.5f * za.y + 0.5f * lrelu(acc[g][1]);
                float z2 = 0.5f * zc.x + 0.5f * lrelu(acc[g][2]);
                float z3 = 0.5f * zc.y + 0.5f * lrelu(acc[g][3]);
                *(uint2*)zp = make_uint2(pk2(z0, z1), pk2(z2, z3));
            } else {              // z4: u16 RMW (img0 in hi half untouched)
                _Float16* pz = (_Float16*)(zp + 8);
                float z4 = 0.5f * (float)pz[0] + 0.5f * lrelu(acc[g][0]);
                pz[0] = (_Float16)z4;
            }
        }
        __syncthreads();                               // B3
    }

    // ================= head: out[o] = <z, wh[o]> + bh[o] =================
    {
        const int yy = tid >> 3, xx0 = (tid & 7) << 2;
        float zf[5][4];
        #pragma unroll
        for (int i = 0; i < 4; ++i) {
            const unsigned* bp = (const unsigned*)((const char*)buf + bofs(yy + 2, xx0 + 2 + i));
            float2 f0 = up2(bp[0]), fb = up2(bp[1]), fc = up2(bp[2]);
            zf[0][i] = f0.x; zf[1][i] = f0.y; zf[2][i] = fb.x; zf[3][i] = fb.y; zf[4][i] = fc.x;
        }
        float ho[10];
        #pragma unroll
        for (int o = 0; o < 10; ++o) ho[o] = 0.f;
        #pragma unroll
        for (int c = 0; c < 5; ++c) {
            #pragma unroll
            for (int o = 0; o < 10; ++o) {
                float4 wv = *(const float4*)&wh[(o * 5 + c) * 1024 + yy * 32 + xx0];
                ho[o] = fmaf(zf[c][0], wv.x, ho[o]);
                ho[o] = fmaf(zf[c][1], wv.y, ho[o]);
                ho[o] = fmaf(zf[c][2], wv.z, ho[o]);
                ho[o] = fmaf(zf[c][3], wv.w, ho[o]);
            }
        }
        #pragma unroll
        for (int m = 1; m < 64; m <<= 1) {
            #pragma unroll
            for (int o = 0; o < 10; ++o) ho[o] += __shfl_xor(ho[o], m);
        }
        if (lane == 0) {
            #pragma unroll
            for (int o = 0; o < 10; ++o) red[wid * 10 + o] = ho[o];
        }
    }
    __syncthreads();
    if (tid < 10)
        out[n * 10 + tid] = red[tid] + red[10 + tid] + red[20 + tid] + red[30 + tid] + bh[tid];
}

extern "C" void kernel_launch(void* const* d_in, const int* in_sizes, int n_in,
                              void* d_out, int out_size, void* d_ws, size_t ws_size,
                              hipStream_t stream) {
    const float* image = (const float*)d_in[0];
    const float* w1    = (const float*)d_in[1];
    const float* b1    = (const float*)d_in[2];
    const float* gam   = (const float*)d_in[3];
    const float* bet   = (const float*)d_in[4];
    const float* w2    = (const float*)d_in[5];
    const float* b2    = (const float*)d_in[6];
    const float* wh    = (const float*)d_in[7];
    const float* bh    = (const float*)d_in[8];
    float* out = (float*)d_out;
    unsigned* ws = (unsigned*)d_ws;

    pack_weights<<<5, 256, 0, stream>>>(w1, w2, ws);

    const int N = in_sizes[0] / (3 * 32 * 32);   // 1024 images
    deq_kernel<<<N, 256, 0, stream>>>(image, ws, b1, gam, bet, b2, wh, bh, out);
}